// Round 1
// baseline (926.060 us; speedup 1.0000x reference)
//
#include <hip/hip_runtime.h>

// dims
#define BB 2
#define SS 1024
#define HH 8
#define DD 64
#define RR 32
#define KK 128
#define ZLEN 1536            // 4K + S
#define ZROW 1152            // staged z positions [K, K+S+K) per (b,r,h,d)
#define QSTRIDE 1028         // 1024 s + 4 dword pad (keeps float4 alignment, breaks bank stride)

// block = (r, h, b); 256 threads; thread t computes s = 4t..4t+3 for all 64 d.
__global__ __launch_bounds__(256) void convspe_kernel(
    const float* __restrict__ q, const float* __restrict__ kmat,
    const float* __restrict__ wq, const float* __restrict__ wk,
    const float* __restrict__ z, float* __restrict__ out)
{
    __shared__ __align__(16) float zrow[ZROW];
    __shared__ __align__(16) float wql[KK];
    __shared__ __align__(16) float wkl[KK];
    __shared__ __align__(16) float qc[8 * QSTRIDE];   // q[s, d0..d0+8) transposed -> [j][s]
    __shared__ __align__(16) float kc[8 * QSTRIDE];

    const int tid = threadIdx.x;
    const int r = blockIdx.x, h = blockIdx.y, b = blockIdx.z;

    const size_t zbase0 = ((size_t)(b * RR + r) * (HH * DD) + (size_t)h * DD) * ZLEN;
    const size_t qkbase = (size_t)b * (SS * HH * DD) + (size_t)h * DD;
    const size_t obase  = (size_t)b * (SS * HH * RR) + (size_t)h * RR + (size_t)r;

    float qacc[4] = {0.f, 0.f, 0.f, 0.f};
    float kacc[4] = {0.f, 0.f, 0.f, 0.f};

    for (int d = 0; d < DD; ++d) {
        const int dl = d & 7;
        __syncthreads();   // previous iteration's LDS reads complete

        if (dl == 0) {
            // stage q/k tiles for d..d+7, transposed to [j][s] for aligned float4 reads
            #pragma unroll 4
            for (int it = 0; it < 32; ++it) {
                const int idx = it * 256 + tid;
                const int s = idx >> 3, j = idx & 7;
                const size_t g = qkbase + (size_t)s * (HH * DD) + (size_t)(d + j);
                qc[j * QSTRIDE + s] = q[g];
                kc[j * QSTRIDE + s] = kmat[g];
            }
        }
        // stage z row (positions K .. K+ZROW) and both weight rows
        {
            const size_t zb_ = zbase0 + (size_t)d * ZLEN + KK;
            #pragma unroll
            for (int i0 = 0; i0 < 5; ++i0) {
                const int idx = i0 * 256 + tid;
                if (idx < ZROW) zrow[idx] = z[zb_ + idx];
            }
            if (tid < KK)       wql[tid]      = wq[(size_t)(h * DD + d) * KK + tid];
            else if (tid < 2*KK) wkl[tid-KK]  = wk[(size_t)(h * DD + d) * KK + (tid - KK)];
        }
        __syncthreads();

        // depthwise conv for this d: cq = conv(z, wk) (-> qbar), ck = conv(z, wq) (-> kbar)
        const float4* Z4  = (const float4*)zrow;
        const float4* WQ4 = (const float4*)wql;
        const float4* WK4 = (const float4*)wkl;

        float cq[4] = {0.f, 0.f, 0.f, 0.f};
        float ck[4] = {0.f, 0.f, 0.f, 0.f};
        float4 za = Z4[tid];                 // z[4t .. 4t+3]
        #pragma unroll
        for (int k4 = 0; k4 < 32; ++k4) {
            const float4 zb = Z4[tid + k4 + 1];     // next 4 z values (max idx 1151, in range)
            const float4 w_q = WQ4[k4];             // uniform -> LDS broadcast
            const float4 w_k = WK4[k4];
            float zw[8];
            zw[0] = za.x; zw[1] = za.y; zw[2] = za.z; zw[3] = za.w;
            zw[4] = zb.x; zw[5] = zb.y; zw[6] = zb.z; zw[7] = zb.w;
            #pragma unroll
            for (int kj = 0; kj < 4; ++kj) {
                const float wqv = (kj == 0) ? w_q.x : (kj == 1) ? w_q.y : (kj == 2) ? w_q.z : w_q.w;
                const float wkv = (kj == 0) ? w_k.x : (kj == 1) ? w_k.y : (kj == 2) ? w_k.z : w_k.w;
                #pragma unroll
                for (int i = 0; i < 4; ++i) {
                    cq[i] = fmaf(wkv, zw[kj + i], cq[i]);   // qbar uses wk (the swap)
                    ck[i] = fmaf(wqv, zw[kj + i], ck[i]);   // kbar uses wq
                }
            }
            za = zb;
        }

        // scale by q/k feature value and accumulate over d
        const float4 qv = *(const float4*)&qc[dl * QSTRIDE + 4 * tid];
        const float4 kv = *(const float4*)&kc[dl * QSTRIDE + 4 * tid];
        qacc[0] = fmaf(qv.x, cq[0], qacc[0]);
        qacc[1] = fmaf(qv.y, cq[1], qacc[1]);
        qacc[2] = fmaf(qv.z, cq[2], qacc[2]);
        qacc[3] = fmaf(qv.w, cq[3], qacc[3]);
        kacc[0] = fmaf(kv.x, ck[0], kacc[0]);
        kacc[1] = fmaf(kv.y, ck[1], kacc[1]);
        kacc[2] = fmaf(kv.z, ck[2], kacc[2]);
        kacc[3] = fmaf(kv.w, ck[3], kacc[3]);
    }

    // store: qhat at [b,s,h,r], khat at +B*S*H*R
    #pragma unroll
    for (int i = 0; i < 4; ++i) {
        const int s = 4 * tid + i;
        out[obase + (size_t)s * (HH * RR)] = qacc[i];
        out[(size_t)(BB * SS * HH * RR) + obase + (size_t)s * (HH * RR)] = kacc[i];
    }
}

extern "C" void kernel_launch(void* const* d_in, const int* in_sizes, int n_in,
                              void* d_out, int out_size, void* d_ws, size_t ws_size,
                              hipStream_t stream) {
    const float* q  = (const float*)d_in[0];
    const float* k  = (const float*)d_in[1];
    const float* wq = (const float*)d_in[2];
    const float* wk = (const float*)d_in[3];
    const float* z  = (const float*)d_in[4];
    float* out = (float*)d_out;

    dim3 grid(RR, HH, BB);   // 512 blocks
    dim3 block(256);
    hipLaunchKernelGGL(convspe_kernel, grid, block, 0, stream, q, k, wq, wk, z, out);
}